// Round 1
// baseline (1354.579 us; speedup 1.0000x reference)
//
#include <hip/hip_runtime.h>

#define N_NODES 100000
#define N_EDGES 500000
#define N_GRAPHS 100
#define DIM 146
#define NPART 128
#define BN_EPS 1e-5f

// ---------------- prep kernels ----------------
__global__ void hist_kernel(const int* __restrict__ src, const int* __restrict__ dst,
                            int* __restrict__ deg_out, int* __restrict__ deg_in) {
  int e = blockIdx.x * 256 + threadIdx.x;
  if (e < N_EDGES) {
    atomicAdd(&deg_out[src[e]], 1);
    atomicAdd(&deg_in[dst[e]], 1);
  }
}

__global__ void norm_kernel(const int* __restrict__ deg_out, const int* __restrict__ deg_in,
                            float* __restrict__ norm_out, float* __restrict__ norm_in) {
  int v = blockIdx.x * 256 + threadIdx.x;
  if (v < N_NODES) {
    norm_out[v] = rsqrtf((float)max(deg_out[v], 1));
    norm_in[v]  = rsqrtf((float)max(deg_in[v], 1));
  }
}

// scan: block = 256 threads, each owns 4 consecutive elements (chunk = 1024)
__global__ void scan1_kernel(const int* __restrict__ deg_in, int* __restrict__ bsums) {
  __shared__ int sred[256];
  int t0 = blockIdx.x * 1024 + threadIdx.x * 4;
  int s = 0;
#pragma unroll
  for (int i = 0; i < 4; i++) { int v = t0 + i; s += (v < N_NODES) ? deg_in[v] : 0; }
  sred[threadIdx.x] = s; __syncthreads();
  for (int off = 128; off > 0; off >>= 1) {
    if (threadIdx.x < off) sred[threadIdx.x] += sred[threadIdx.x + off];
    __syncthreads();
  }
  if (threadIdx.x == 0) bsums[blockIdx.x] = sred[0];
}

__global__ void scan2_kernel(const int* __restrict__ bsums, int* __restrict__ bofs,
                             int* __restrict__ row_ptr, int nb) {
  if (threadIdx.x == 0 && blockIdx.x == 0) {
    int run = 0;
    for (int i = 0; i < nb; i++) { bofs[i] = run; run += bsums[i]; }
    row_ptr[N_NODES] = run;
  }
}

__global__ void scan3_kernel(const int* __restrict__ deg_in, const int* __restrict__ bofs,
                             int* __restrict__ row_ptr) {
  __shared__ int ssc[256];
  int t0 = blockIdx.x * 1024 + threadIdx.x * 4;
  int v4[4]; int s = 0;
#pragma unroll
  for (int i = 0; i < 4; i++) { int v = t0 + i; v4[i] = (v < N_NODES) ? deg_in[v] : 0; s += v4[i]; }
  ssc[threadIdx.x] = s; __syncthreads();
  for (int off = 1; off < 256; off <<= 1) {
    int t = (threadIdx.x >= off) ? ssc[threadIdx.x - off] : 0;
    __syncthreads();
    ssc[threadIdx.x] += t;
    __syncthreads();
  }
  int ex = ssc[threadIdx.x] - s + bofs[blockIdx.x];
#pragma unroll
  for (int i = 0; i < 4; i++) {
    int v = t0 + i;
    if (v < N_NODES) { row_ptr[v] = ex; ex += v4[i]; }
  }
}

__global__ void csr_fill_kernel(const int* __restrict__ src, const int* __restrict__ dst,
                                const int* __restrict__ row_ptr, int* __restrict__ fill,
                                int* __restrict__ csr) {
  int e = blockIdx.x * 256 + threadIdx.x;
  if (e < N_EDGES) {
    int d = dst[e];
    int slot = atomicAdd(&fill[d], 1);
    csr[row_ptr[d] + slot] = src[e];
  }
}

// ---------------- GEMM: out = A @ W + b  (optionally *snorm, +col stats) ----------------
// 64 rows/block, full K=146. A tile staged in LDS (enables in-place A==out).
template <bool LAYER>
__global__ __launch_bounds__(256) void gemm_kernel(
    const float* __restrict__ A, const float* __restrict__ W, const float* __restrict__ bias,
    const float* __restrict__ snorm, float* __restrict__ out, float* __restrict__ stats) {
  __shared__ float sA[64 * 148];
  __shared__ float sred[2 * DIM];
  int r0 = blockIdx.x * 64;
  int rows = min(64, N_NODES - r0);
  const float* Ab = A + (size_t)r0 * DIM;
  for (int i = threadIdx.x; i < rows * DIM; i += 256) {
    int r = i / DIM, c = i - r * DIM;
    sA[r * 148 + c] = Ab[i];
  }
  for (int i = rows * DIM + threadIdx.x; i < 64 * DIM; i += 256) {
    int r = i / DIM, c = i - r * DIM;
    sA[r * 148 + c] = 0.f;
  }
  if (LAYER) { for (int i = threadIdx.x; i < 2 * DIM; i += 256) sred[i] = 0.f; }
  __syncthreads();

  int tx = threadIdx.x & 31, ty = threadIdx.x >> 5;
  float acc[8][5];
#pragma unroll
  for (int i = 0; i < 8; i++)
#pragma unroll
    for (int j = 0; j < 5; j++) acc[i][j] = 0.f;

#pragma unroll 2
  for (int k = 0; k < DIM; k++) {
    float a[8];
#pragma unroll
    for (int i = 0; i < 8; i++) a[i] = sA[(ty * 8 + i) * 148 + k];
    const float* Wr = W + k * DIM + tx;
    float w[5];
#pragma unroll
    for (int j = 0; j < 5; j++) w[j] = (j < 4 || tx < 18) ? Wr[32 * j] : 0.f;
#pragma unroll
    for (int i = 0; i < 8; i++)
#pragma unroll
      for (int j = 0; j < 5; j++) acc[i][j] = fmaf(a[i], w[j], acc[i][j]);
  }

#pragma unroll
  for (int j = 0; j < 5; j++) {
    int c = tx + 32 * j;
    if (c < DIM) {
      float b = bias[c];
      float ssum = 0.f, ssq = 0.f;
#pragma unroll
      for (int i = 0; i < 8; i++) {
        int r = r0 + ty * 8 + i;
        if (r < N_NODES) {
          float val = acc[i][j] + b;
          if (LAYER) val *= snorm[r];
          out[(size_t)r * DIM + c] = val;
          ssum += val; ssq += val * val;
        }
      }
      if (LAYER) {
        atomicAdd(&sred[c], ssum);
        atomicAdd(&sred[DIM + c], ssq);
      }
    }
  }
  if (LAYER) {
    __syncthreads();
    for (int i = threadIdx.x; i < 2 * DIM; i += 256) atomicAdd(&stats[i], sred[i]);
  }
}

// ---------------- aggregation: one wave per destination node ----------------
__global__ __launch_bounds__(256) void agg_kernel(
    const float* __restrict__ h, const int* __restrict__ row_ptr, const int* __restrict__ csr,
    const float* __restrict__ norm_out, const float* __restrict__ norm_in, float* __restrict__ out) {
  int wid = threadIdx.x >> 6, lane = threadIdx.x & 63;
  int v = blockIdx.x * 4 + wid;
  if (v >= N_NODES) return;
  int e0 = row_ptr[v], e1 = row_ptr[v + 1];
  float a0 = 0.f, a1 = 0.f, a2 = 0.f;
  for (int e = e0; e < e1; e++) {
    int s = csr[e];
    float sc = norm_out[s];
    const float* hr = h + (size_t)s * DIM;
    a0 = fmaf(hr[lane], sc, a0);
    a1 = fmaf(hr[lane + 64], sc, a1);
    if (lane < 18) a2 = fmaf(hr[lane + 128], sc, a2);
  }
  float ni = norm_in[v];
  float* ow = out + (size_t)v * DIM;
  ow[lane] = a0 * ni;
  ow[lane + 64] = a1 * ni;
  if (lane < 18) ow[lane + 128] = a2 * ni;
}

// ---------------- BN prep: per-column scale/shift from sums ----------------
__global__ void bnprep_kernel(float* __restrict__ stats, const float* __restrict__ gamma,
                              const float* __restrict__ beta) {
  int c = threadIdx.x;
  if (c < DIM) {
    float mu = stats[c] * (1.f / N_NODES);
    float var = stats[DIM + c] * (1.f / N_NODES) - mu * mu;
    float rs = rsqrtf(var + BN_EPS);
    float sc = gamma[c] * rs;
    stats[2 * DIM + c] = sc;
    stats[3 * DIM + c] = beta[c] - mu * sc;
  }
}

// ---------------- BN + ReLU + residual (in-place on h) ----------------
__global__ __launch_bounds__(256) void bn_kernel(const float* __restrict__ tmp,
                                                 const float* __restrict__ stats,
                                                 float* __restrict__ h) {
  int idx = blockIdx.x * 256 + threadIdx.x;
  if (idx >= N_NODES * (DIM / 2)) return;
  int v = idx / (DIM / 2), c2 = idx - v * (DIM / 2), c = 2 * c2;
  float2 t = *(const float2*)(tmp + (size_t)v * DIM + c);
  float2 sc = *(const float2*)(stats + 2 * DIM + c);
  float2 sh = *(const float2*)(stats + 3 * DIM + c);
  float2* hp = (float2*)(h + (size_t)v * DIM + c);
  float2 hv = *hp;
  float x0 = fmaf(t.x, sc.x, sh.x); x0 = x0 > 0.f ? x0 : 0.f;
  float x1 = fmaf(t.y, sc.y, sh.y); x1 = x1 > 0.f ? x1 : 0.f;
  hv.x += x0; hv.y += x1;
  *hp = hv;
}

// ---------------- per-graph sum with partitioned atomics ----------------
__global__ void gsum_kernel(const float* __restrict__ h, const int* __restrict__ gids,
                            float* __restrict__ hgp, int* __restrict__ cntp) {
  int idx = blockIdx.x * 256 + threadIdx.x;
  if (idx >= N_NODES * DIM) return;
  int v = idx / DIM, d = idx - v * DIM;
  int g = gids[v];
  int p = blockIdx.x & (NPART - 1);
  atomicAdd(&hgp[(size_t)p * N_GRAPHS * DIM + g * DIM + d], h[idx]);
  if (d == 0) atomicAdd(&cntp[p * N_GRAPHS + g], 1);
}

// ---------------- fused mean + MLP readout: one block per graph ----------------
__global__ __launch_bounds__(256) void mlp_kernel(
    const float* __restrict__ hgp, const int* __restrict__ cntp,
    const float* __restrict__ W1, const float* __restrict__ b1,
    const float* __restrict__ W2, const float* __restrict__ b2,
    const float* __restrict__ W3, const float* __restrict__ b3,
    float* __restrict__ out) {
  __shared__ float hrow[DIM];
  __shared__ float x1[73];
  __shared__ float x2[36];
  __shared__ float cnt_s;
  int g = blockIdx.x;
  int t = threadIdx.x;
  if (t == 0) {
    int c = 0;
    for (int p = 0; p < NPART; p++) c += cntp[p * N_GRAPHS + g];
    cnt_s = (float)c;
  }
  __syncthreads();
  if (t < DIM) {
    float s = 0.f;
    for (int p = 0; p < NPART; p++) s += hgp[(size_t)p * N_GRAPHS * DIM + g * DIM + t];
    hrow[t] = s / cnt_s;
  }
  __syncthreads();
  if (t < 73) {
    float s = b1[t];
    for (int k = 0; k < DIM; k++) s = fmaf(hrow[k], W1[k * 73 + t], s);
    x1[t] = s > 0.f ? s : 0.f;
  }
  __syncthreads();
  if (t < 36) {
    float s = b2[t];
    for (int k = 0; k < 73; k++) s = fmaf(x1[k], W2[k * 36 + t], s);
    x2[t] = s > 0.f ? s : 0.f;
  }
  __syncthreads();
  if (t < 10) {
    float s = b3[t];
    for (int k = 0; k < 36; k++) s = fmaf(x2[k], W3[k * 10 + t], s);
    out[g * 10 + t] = s;
  }
}

extern "C" void kernel_launch(void* const* d_in, const int* in_sizes, int n_in,
                              void* d_out, int out_size, void* d_ws, size_t ws_size,
                              hipStream_t stream) {
  const float* nodes_feat = (const float*)d_in[0];
  const float* snorm  = (const float*)d_in[1];
  const float* W_emb  = (const float*)d_in[2];
  const float* b_emb  = (const float*)d_in[3];
  const float* Ws     = (const float*)d_in[4];
  const float* bs     = (const float*)d_in[5];
  const float* gammas = (const float*)d_in[6];
  const float* betas  = (const float*)d_in[7];
  const float* W1 = (const float*)d_in[8];
  const float* b1 = (const float*)d_in[9];
  const float* W2 = (const float*)d_in[10];
  const float* b2 = (const float*)d_in[11];
  const float* W3 = (const float*)d_in[12];
  const float* b3 = (const float*)d_in[13];
  const int* src  = (const int*)d_in[14];
  const int* dst  = (const int*)d_in[15];
  const int* gids = (const int*)d_in[16];
  float* out = (float*)d_out;

  char* base = (char*)d_ws;
  size_t off = 0;
  auto alloc = [&](size_t bytes) { void* p = base + off; off += (bytes + 255) & ~size_t(255); return p; };
  float* h   = (float*)alloc((size_t)N_NODES * DIM * 4);
  float* tmp = (float*)alloc((size_t)N_NODES * DIM * 4);
  char* zstart = base + off;
  int* deg_out = (int*)alloc(N_NODES * 4);
  int* deg_in  = (int*)alloc(N_NODES * 4);
  int* fill    = (int*)alloc(N_NODES * 4);
  float* stats = (float*)alloc(4 * 4 * DIM * 4);   // per layer: [sum, sumsq, scale, shift]
  float* hgp   = (float*)alloc((size_t)NPART * N_GRAPHS * DIM * 4);
  int* cntp    = (int*)alloc(NPART * N_GRAPHS * 4);
  size_t zbytes = (size_t)((base + off) - zstart);
  int* row_ptr = (int*)alloc((N_NODES + 1) * 4);
  float* norm_out = (float*)alloc(N_NODES * 4);
  float* norm_in  = (float*)alloc(N_NODES * 4);
  int* csr   = (int*)alloc((size_t)N_EDGES * 4);
  int* bsums = (int*)alloc(128 * 4);
  int* bofs  = (int*)alloc(128 * 4);

  hipMemsetAsync(zstart, 0, zbytes, stream);

  hist_kernel<<<(N_EDGES + 255) / 256, 256, 0, stream>>>(src, dst, deg_out, deg_in);
  norm_kernel<<<(N_NODES + 255) / 256, 256, 0, stream>>>(deg_out, deg_in, norm_out, norm_in);
  int nb = (N_NODES + 1023) / 1024;
  scan1_kernel<<<nb, 256, 0, stream>>>(deg_in, bsums);
  scan2_kernel<<<1, 64, 0, stream>>>(bsums, bofs, row_ptr, nb);
  scan3_kernel<<<nb, 256, 0, stream>>>(deg_in, bofs, row_ptr);
  csr_fill_kernel<<<(N_EDGES + 255) / 256, 256, 0, stream>>>(src, dst, row_ptr, fill, csr);

  gemm_kernel<false><<<(N_NODES + 63) / 64, 256, 0, stream>>>(nodes_feat, W_emb, b_emb, nullptr, h, nullptr);

  for (int l = 0; l < 4; l++) {
    float* st = stats + l * 4 * DIM;
    agg_kernel<<<(N_NODES + 3) / 4, 256, 0, stream>>>(h, row_ptr, csr, norm_out, norm_in, tmp);
    gemm_kernel<true><<<(N_NODES + 63) / 64, 256, 0, stream>>>(tmp, Ws + (size_t)l * DIM * DIM,
                                                               bs + l * DIM, snorm, tmp, st);
    bnprep_kernel<<<1, 192, 0, stream>>>(st, gammas + l * DIM, betas + l * DIM);
    bn_kernel<<<(N_NODES * (DIM / 2) + 255) / 256, 256, 0, stream>>>(tmp, st, h);
  }

  gsum_kernel<<<(N_NODES * DIM + 255) / 256, 256, 0, stream>>>(h, gids, hgp, cntp);
  mlp_kernel<<<N_GRAPHS, 256, 0, stream>>>(hgp, cntp, W1, b1, W2, b2, W3, b3, out);
}